// Round 1
// baseline (10046.091 us; speedup 1.0000x reference)
//
#include <hip/hip_runtime.h>

// ---- problem dims ----
#define NB 4096    // total peds (B)
#define HD 128     // H
#define ED 64      // E
#define PMD 512    // PM
#define BND 1024   // BN
#define NF 128     // frames
#define NP 32      // peds/frame
#define TSTEPS 12

typedef __attribute__((ext_vector_type(8))) short short8;
typedef __attribute__((ext_vector_type(8))) __bf16 bf16x8;
typedef __attribute__((ext_vector_type(4))) float f32x4;

#define MFMA16(a, b, c) __builtin_amdgcn_mfma_f32_16x16x32_bf16((a), (b), (c), 0, 0, 0)

__device__ __forceinline__ unsigned short f2bf(float f) {
  unsigned int x = __float_as_uint(f);
  x += 0x7fffu + ((x >> 16) & 1u);
  return (unsigned short)(x >> 16);
}

__device__ __forceinline__ float sigm(float x) { return 1.0f / (1.0f + expf(-x)); }

// ---------------- pre-pass packs ----------------

// Transpose W (K x N, fp32) -> Wt (N x K, bf16), 32x32 LDS tiles.
__global__ __launch_bounds__(256) void k_transpose_bf(const float* __restrict__ W,
                                                      unsigned short* __restrict__ Wt,
                                                      int K, int N) {
  __shared__ float t[32][33];
  int nb = blockIdx.x * 32, kb = blockIdx.y * 32;
  int tx = threadIdx.x & 31, ty = threadIdx.x >> 5;  // 8 rows of 32
  #pragma unroll
  for (int r = 0; r < 32; r += 8)
    t[ty + r][tx] = W[(size_t)(kb + ty + r) * N + nb + tx];
  __syncthreads();
  #pragma unroll
  for (int r = 0; r < 32; r += 8)
    Wt[(size_t)(nb + ty + r) * K + kb + tx] = f2bf(t[tx][ty + r]);
}

// WihT[64][512], WhhT[128][512] fp32 transposes (small, once per call)
__global__ __launch_bounds__(256) void k_pack_lstm_w(const float* __restrict__ Wih,
                                                     const float* __restrict__ Whh,
                                                     float* __restrict__ WihT,
                                                     float* __restrict__ WhhT) {
  int idx = blockIdx.x * 256 + threadIdx.x;
  if (idx < 64 * 512) { int k = idx >> 9, n = idx & 511; WihT[idx] = Wih[n * 64 + k]; }
  if (idx < 128 * 512) { int k = idx >> 9, n = idx & 511; WhhT[idx] = Whh[n * 128 + k]; }
}

// Wpp[n][2] = (W_pe @ W_p1[:64])^T ; cvec[n] = b_pe @ W_p1[:64,n] + b_p1[n]
__global__ __launch_bounds__(256) void k_pack_wpp(const float* __restrict__ Wpe,
                                                  const float* __restrict__ bpe,
                                                  const float* __restrict__ Wp1,
                                                  const float* __restrict__ bp1,
                                                  float* __restrict__ Wpp,
                                                  float* __restrict__ cvec) {
  int n = blockIdx.x * 256 + threadIdx.x;
  if (n >= 512) return;
  float s0 = 0.f, s1 = 0.f, sc = 0.f;
  for (int k = 0; k < 64; ++k) {
    float w = Wp1[k * 512 + n];
    s0 += Wpe[k] * w;
    s1 += Wpe[64 + k] * w;
    sc += bpe[k] * w;
  }
  Wpp[n * 2] = s0; Wpp[n * 2 + 1] = s1; cvec[n] = sc + bp1[n];
}

// x0 = obs_final_pos_rel @ W_emb + b_emb
__global__ __launch_bounds__(256) void k_x0(const float* __restrict__ ofr,
                                            const float* __restrict__ Wemb,
                                            const float* __restrict__ bemb,
                                            float* __restrict__ x) {
  int idx = blockIdx.x * 256 + threadIdx.x;
  if (idx >= NB * ED) return;
  int row = idx >> 6, e = idx & 63;
  x[idx] = bemb[e] + ofr[row * 2] * Wemb[e] + ofr[row * 2 + 1] * Wemb[64 + e];
}

// ---------------- per-step kernels ----------------

// K1: LSTM cell + rel/curr pos + x_new + output writes. 8 rows/block, 256 thr.
__global__ __launch_bounds__(256) void k1_lstm(
    const float* __restrict__ x, const float* __restrict__ hin, const float* __restrict__ cin,
    const float* __restrict__ WihT, const float* __restrict__ WhhT,
    const float* __restrict__ bih, const float* __restrict__ bhh,
    const float* __restrict__ Wpos, const float* __restrict__ bpos,
    const float* __restrict__ Wemb, const float* __restrict__ bemb,
    const float* __restrict__ lastpos,
    float* __restrict__ cout, float* __restrict__ hnew, unsigned short* __restrict__ mi,
    float* __restrict__ posout, float* __restrict__ xout,
    float* __restrict__ outc, float* __restrict__ outr) {
  __shared__ float xh[8][192];
  __shared__ float hnl[8][128];
  __shared__ float rp[8][2];
  int tid = threadIdx.x;
  int r0 = blockIdx.x * 8;
  for (int idx = tid; idx < 8 * 192; idx += 256) {
    int r = idx / 192, k = idx % 192;
    xh[r][k] = (k < 64) ? x[(r0 + r) * 64 + k] : hin[(r0 + r) * 128 + (k - 64)];
  }
  __syncthreads();
  int j = tid & 127, rg = tid >> 7;
  float acc0[4], acc1[4], acc2[4], acc3[4];
  {
    float b0 = bih[j] + bhh[j];
    float b1 = bih[128 + j] + bhh[128 + j];
    float b2 = bih[256 + j] + bhh[256 + j];
    float b3 = bih[384 + j] + bhh[384 + j];
    #pragma unroll
    for (int r = 0; r < 4; ++r) { acc0[r] = b0; acc1[r] = b1; acc2[r] = b2; acc3[r] = b3; }
  }
  for (int k = 0; k < 64; ++k) {
    float w0 = WihT[k * 512 + j], w1 = WihT[k * 512 + 128 + j],
          w2 = WihT[k * 512 + 256 + j], w3 = WihT[k * 512 + 384 + j];
    #pragma unroll
    for (int r = 0; r < 4; ++r) {
      float xv = xh[rg * 4 + r][k];
      acc0[r] += w0 * xv; acc1[r] += w1 * xv; acc2[r] += w2 * xv; acc3[r] += w3 * xv;
    }
  }
  for (int k = 0; k < 128; ++k) {
    float w0 = WhhT[k * 512 + j], w1 = WhhT[k * 512 + 128 + j],
          w2 = WhhT[k * 512 + 256 + j], w3 = WhhT[k * 512 + 384 + j];
    #pragma unroll
    for (int r = 0; r < 4; ++r) {
      float hv = xh[rg * 4 + r][64 + k];
      acc0[r] += w0 * hv; acc1[r] += w1 * hv; acc2[r] += w2 * hv; acc3[r] += w3 * hv;
    }
  }
  #pragma unroll
  for (int r = 0; r < 4; ++r) {
    int row = r0 + rg * 4 + r;
    float ig = sigm(acc0[r]), fg = sigm(acc1[r]), gg = tanhf(acc2[r]), og = sigm(acc3[r]);
    float cn = fg * cin[row * 128 + j] + ig * gg;
    float hv = og * tanhf(cn);
    cout[row * 128 + j] = cn;
    hnew[row * 128 + j] = hv;
    mi[(size_t)row * 1152 + j] = f2bf(hv);
    hnl[rg * 4 + r][j] = hv;
  }
  __syncthreads();
  if (tid < 16) {
    int r = tid >> 1, d = tid & 1, row = r0 + r;
    float s = bpos[d];
    for (int k = 0; k < 128; ++k) s += hnl[r][k] * Wpos[k * 2 + d];
    float cur = s + lastpos[row * 2 + d];
    rp[r][d] = s;
    posout[row * 2 + d] = cur;
    outc[row * 2 + d] = cur;
    outr[row * 2 + d] = s;
  }
  __syncthreads();
  for (int idx = tid; idx < 8 * 64; idx += 256) {
    int r = idx >> 6, e = idx & 63;
    xout[(r0 + r) * 64 + e] = bemb[e] + rp[r][0] * Wemb[e] + rp[r][1] * Wemb[64 + e];
  }
}

// K2: u[b][n] = pos_b.Wpp[:,n] + h_b.Wp1[64:,n] + cvec[n] ; v[b][n] = pos_b.Wpp[:,n]
__global__ __launch_bounds__(256) void k2_uv(
    const float* __restrict__ hnew, const float* __restrict__ pos,
    const float* __restrict__ Wp1, const float* __restrict__ Wpp,
    const float* __restrict__ cvec, float* __restrict__ u, float* __restrict__ v) {
  __shared__ float h8[8][128];
  __shared__ float p8[8][2];
  int tid = threadIdx.x, r0 = blockIdx.x * 8;
  for (int idx = tid; idx < 1024; idx += 256) {
    int r = idx >> 7, k = idx & 127;
    h8[r][k] = hnew[(r0 + r) * 128 + k];
  }
  if (tid < 16) p8[tid >> 1][tid & 1] = pos[r0 * 2 + tid];
  __syncthreads();
  int n = tid, n2 = tid + 256;
  float aA[8], aB[8];
  #pragma unroll
  for (int r = 0; r < 8; ++r) { aA[r] = 0.f; aB[r] = 0.f; }
  for (int k = 0; k < 128; ++k) {
    float wA = Wp1[(64 + k) * 512 + n], wB = Wp1[(64 + k) * 512 + n2];
    #pragma unroll
    for (int r = 0; r < 8; ++r) { aA[r] += wA * h8[r][k]; aB[r] += wB * h8[r][k]; }
  }
  float wp0A = Wpp[n * 2], wp1A = Wpp[n * 2 + 1], cA = cvec[n];
  float wp0B = Wpp[n2 * 2], wp1B = Wpp[n2 * 2 + 1], cB = cvec[n2];
  #pragma unroll
  for (int r = 0; r < 8; ++r) {
    int row = r0 + r;
    float t0 = p8[r][0] * wp0A + p8[r][1] * wp1A;
    v[(size_t)row * 512 + n] = t0;
    u[(size_t)row * 512 + n] = t0 + aA[r] + cA;
    float t1 = p8[r][0] * wp0B + p8[r][1] * wp1B;
    v[(size_t)row * 512 + n2] = t1;
    u[(size_t)row * 512 + n2] = t1 + aB[r] + cB;
  }
}

__device__ __forceinline__ bf16x8 make_a(const float* __restrict__ up, float4 va, float4 vb) {
  float4 ua = *(const float4*)up;
  float4 ub = *(const float4*)(up + 4);
  union { short8 s; bf16x8 b; } r;
  r.s[0] = (short)f2bf(fmaxf(ua.x - va.x, 0.f));
  r.s[1] = (short)f2bf(fmaxf(ua.y - va.y, 0.f));
  r.s[2] = (short)f2bf(fmaxf(ua.z - va.z, 0.f));
  r.s[3] = (short)f2bf(fmaxf(ua.w - va.w, 0.f));
  r.s[4] = (short)f2bf(fmaxf(ub.x - vb.x, 0.f));
  r.s[5] = (short)f2bf(fmaxf(ub.y - vb.y, 0.f));
  r.s[6] = (short)f2bf(fmaxf(ub.z - vb.z, 0.f));
  r.s[7] = (short)f2bf(fmaxf(ub.w - vb.w, 0.f));
  return r.b;
}

// K3: per frame f, per ped i: pool_h[f,i,n] = relu(max_j ( relu(u_j - v_i) @ Wp2 )[n] + bp2[n])
// grid 4096 = f(128) x iblk(8) x nblk(4); 512 thr = 8 waves (4 i x 2 n-halves)
// wave tile: 32 rows (j) x 128 cols, K=512, bf16 MFMA 16x16x32, A built on the fly.
__global__ __launch_bounds__(512) void k3_pool(
    const float* __restrict__ u, const float* __restrict__ v,
    const unsigned short* __restrict__ Bt, const float* __restrict__ bp2,
    unsigned short* __restrict__ mi) {
  int bid = blockIdx.x;
  int f = bid & 127, iblk = (bid >> 7) & 7, nblk = bid >> 10;
  int tid = threadIdx.x, wid = tid >> 6, lane = tid & 63;
  int i = iblk * 4 + (wid >> 1);
  int nc0 = nblk * 256 + (wid & 1) * 128;
  int c = lane & 15, q = lane >> 4;
  const float* u0 = u + (size_t)(f * 32 + c) * 512;
  const float* u1 = u0 + 16 * 512;
  const float* vp = v + (size_t)(f * 32 + i) * 512;
  f32x4 acc[2][8];
  #pragma unroll
  for (int a = 0; a < 2; ++a)
    #pragma unroll
    for (int b = 0; b < 8; ++b) acc[a][b] = (f32x4){0.f, 0.f, 0.f, 0.f};
  const unsigned short* bb = Bt + (size_t)(nc0 + c) * 512;
  for (int ks = 0; ks < 16; ++ks) {
    int k0 = ks * 32 + q * 8;
    float4 v0 = *(const float4*)(vp + k0);
    float4 v1 = *(const float4*)(vp + k0 + 4);
    bf16x8 a0 = make_a(u0 + k0, v0, v1);
    bf16x8 a1 = make_a(u1 + k0, v0, v1);
    #pragma unroll
    for (int nt = 0; nt < 8; ++nt) {
      bf16x8 bf = *(const bf16x8*)(bb + (size_t)nt * 16 * 512 + k0);
      acc[0][nt] = MFMA16(a0, bf, acc[0][nt]);
      acc[1][nt] = MFMA16(a1, bf, acc[1][nt]);
    }
  }
  #pragma unroll
  for (int nt = 0; nt < 8; ++nt) {
    float m = acc[0][nt][0];
    #pragma unroll
    for (int r = 0; r < 4; ++r) { m = fmaxf(m, acc[0][nt][r]); m = fmaxf(m, acc[1][nt][r]); }
    m = fmaxf(m, __shfl_xor(m, 16));
    m = fmaxf(m, __shfl_xor(m, 32));
    int n = nc0 + nt * 16 + c;
    m = fmaxf(m + bp2[n], 0.0f);
    if (q == 0) mi[(size_t)(f * 32 + i) * 1152 + 128 + n] = f2bf(m);
  }
}

// K4: nh1 = relu(mi @ W_m1 + b_m1), M=4096 K=1152 N=1024 (bf16 MFMA)
// grid 256 = mb(64) x nb(4); 8 waves (2 m x 4 n), wave tile 32x64
__global__ __launch_bounds__(512) void k4_mlp1(
    const unsigned short* __restrict__ mi, const unsigned short* __restrict__ Wt,
    const float* __restrict__ bm1, unsigned short* __restrict__ nh1) {
  int bid = blockIdx.x;
  int mb = bid & 63, nb = bid >> 6;
  int tid = threadIdx.x, wid = tid >> 6, lane = tid & 63;
  int row0 = mb * 64 + (wid >> 2) * 32;
  int nc0 = nb * 256 + (wid & 3) * 64;
  int c = lane & 15, q = lane >> 4;
  const unsigned short* a0p = mi + (size_t)(row0 + c) * 1152;
  const unsigned short* a1p = a0p + 16 * 1152;
  const unsigned short* bb = Wt + (size_t)(nc0 + c) * 1152;
  f32x4 acc[2][4];
  #pragma unroll
  for (int a = 0; a < 2; ++a)
    #pragma unroll
    for (int b = 0; b < 4; ++b) acc[a][b] = (f32x4){0.f, 0.f, 0.f, 0.f};
  for (int ks = 0; ks < 36; ++ks) {
    int k0 = ks * 32 + q * 8;
    bf16x8 a0 = *(const bf16x8*)(a0p + k0);
    bf16x8 a1 = *(const bf16x8*)(a1p + k0);
    #pragma unroll
    for (int nt = 0; nt < 4; ++nt) {
      bf16x8 bf = *(const bf16x8*)(bb + (size_t)nt * 16 * 1152 + k0);
      acc[0][nt] = MFMA16(a0, bf, acc[0][nt]);
      acc[1][nt] = MFMA16(a1, bf, acc[1][nt]);
    }
  }
  #pragma unroll
  for (int mt = 0; mt < 2; ++mt)
    #pragma unroll
    for (int nt = 0; nt < 4; ++nt)
      #pragma unroll
      for (int r = 0; r < 4; ++r) {
        int row = row0 + mt * 16 + q * 4 + r;
        int col = nc0 + nt * 16 + c;
        float val = fmaxf(acc[mt][nt][r] + bm1[col], 0.f);
        nh1[(size_t)row * 1024 + col] = f2bf(val);
      }
}

// K5: h = relu(nh1 @ W_m2 + b_m2), M=4096 K=1024 N=128
// grid 64; 8 waves (4 m x 2 n), wave tile 16x64
__global__ __launch_bounds__(512) void k5_mlp2(
    const unsigned short* __restrict__ nh1, const unsigned short* __restrict__ Wt,
    const float* __restrict__ bm2, float* __restrict__ hout) {
  int bid = blockIdx.x;
  int tid = threadIdx.x, wid = tid >> 6, lane = tid & 63;
  int row0 = bid * 64 + (wid >> 1) * 16;
  int nc0 = (wid & 1) * 64;
  int c = lane & 15, q = lane >> 4;
  const unsigned short* ap = nh1 + (size_t)(row0 + c) * 1024;
  const unsigned short* bb = Wt + (size_t)(nc0 + c) * 1024;
  f32x4 acc[4];
  #pragma unroll
  for (int b = 0; b < 4; ++b) acc[b] = (f32x4){0.f, 0.f, 0.f, 0.f};
  for (int ks = 0; ks < 32; ++ks) {
    int k0 = ks * 32 + q * 8;
    bf16x8 a = *(const bf16x8*)(ap + k0);
    #pragma unroll
    for (int nt = 0; nt < 4; ++nt) {
      bf16x8 bf = *(const bf16x8*)(bb + (size_t)nt * 16 * 1024 + k0);
      acc[nt] = MFMA16(a, bf, acc[nt]);
    }
  }
  #pragma unroll
  for (int nt = 0; nt < 4; ++nt)
    #pragma unroll
    for (int r = 0; r < 4; ++r) {
      int row = row0 + q * 4 + r;
      int col = nc0 + nt * 16 + c;
      hout[(size_t)row * 128 + col] = fmaxf(acc[nt][r] + bm2[col], 0.f);
    }
}

// ---------------- host ----------------

extern "C" void kernel_launch(void* const* d_in, const int* in_sizes, int n_in,
                              void* d_out, int out_size, void* d_ws, size_t ws_size,
                              hipStream_t stream) {
  const float* h0   = (const float*)d_in[0];
  const float* c0   = (const float*)d_in[1];
  const float* ofp  = (const float*)d_in[2];
  const float* ofr  = (const float*)d_in[3];
  const float* Wemb = (const float*)d_in[4];
  const float* bemb = (const float*)d_in[5];
  const float* Wih  = (const float*)d_in[6];
  const float* Whh  = (const float*)d_in[7];
  const float* bih  = (const float*)d_in[8];
  const float* bhh  = (const float*)d_in[9];
  const float* Wpos = (const float*)d_in[10];
  const float* bpos = (const float*)d_in[11];
  const float* Wpe  = (const float*)d_in[12];
  const float* bpe  = (const float*)d_in[13];
  const float* Wp1  = (const float*)d_in[14];
  const float* bp1  = (const float*)d_in[15];
  const float* Wp2  = (const float*)d_in[16];
  const float* bp2  = (const float*)d_in[17];
  const float* Wm1  = (const float*)d_in[18];
  const float* bm1  = (const float*)d_in[19];
  const float* Wm2  = (const float*)d_in[20];
  const float* bm2  = (const float*)d_in[21];
  // d_in[22]: seq_start_end (uniform frames of 32 -- not needed)

  char* ws = (char*)d_ws;
  size_t off = 0;
  auto alloc = [&](size_t bytes) {
    char* p = ws + off;
    off += (bytes + 255) & ~(size_t)255;
    return p;
  };
  float* h    = (float*)alloc((size_t)NB * HD * 4);
  float* cst  = (float*)alloc((size_t)NB * HD * 4);
  float* hnew = (float*)alloc((size_t)NB * HD * 4);
  float* xbuf = (float*)alloc((size_t)NB * ED * 4);
  float* pos  = (float*)alloc((size_t)NB * 2 * 4);
  float* u    = (float*)alloc((size_t)NB * 512 * 4);
  float* v    = (float*)alloc((size_t)NB * 512 * 4);
  unsigned short* mi   = (unsigned short*)alloc((size_t)NB * 1152 * 2);
  unsigned short* nh1  = (unsigned short*)alloc((size_t)NB * 1024 * 2);
  float* WihT = (float*)alloc(64 * 512 * 4);
  float* WhhT = (float*)alloc(128 * 512 * 4);
  float* Wpp  = (float*)alloc(512 * 2 * 4);
  float* cvec = (float*)alloc(512 * 4);
  unsigned short* Bt2  = (unsigned short*)alloc((size_t)1024 * 512 * 2);
  unsigned short* Wm1t = (unsigned short*)alloc((size_t)1024 * 1152 * 2);
  unsigned short* Wm2t = (unsigned short*)alloc((size_t)128 * 1024 * 2);

  float* outc = (float*)d_out;
  float* outr = outc + (size_t)TSTEPS * NB * 2;

  // weight packs (cheap, run every call -- deterministic)
  k_pack_lstm_w<<<256, 256, 0, stream>>>(Wih, Whh, WihT, WhhT);
  k_pack_wpp<<<2, 256, 0, stream>>>(Wpe, bpe, Wp1, bp1, Wpp, cvec);
  k_transpose_bf<<<dim3(1024 / 32, 512 / 32), 256, 0, stream>>>(Wp2, Bt2, 512, 1024);
  k_transpose_bf<<<dim3(1024 / 32, 1152 / 32), 256, 0, stream>>>(Wm1, Wm1t, 1152, 1024);
  k_transpose_bf<<<dim3(128 / 32, 1024 / 32), 256, 0, stream>>>(Wm2, Wm2t, 1024, 128);
  k_x0<<<NB * ED / 256, 256, 0, stream>>>(ofr, Wemb, bemb, xbuf);

  for (int t = 0; t < TSTEPS; ++t) {
    const float* hin = (t == 0) ? h0 : h;
    const float* cin = (t == 0) ? c0 : cst;
    const float* lp  = (t == 0) ? ofp : pos;
    k1_lstm<<<NB / 8, 256, 0, stream>>>(xbuf, hin, cin, WihT, WhhT, bih, bhh, Wpos, bpos,
                                        Wemb, bemb, lp, cst, hnew, mi, pos, xbuf,
                                        outc + (size_t)t * NB * 2, outr + (size_t)t * NB * 2);
    k2_uv<<<NB / 8, 256, 0, stream>>>(hnew, pos, Wp1, Wpp, cvec, u, v);
    k3_pool<<<4096, 512, 0, stream>>>(u, v, Bt2, bp2, mi);
    k4_mlp1<<<256, 512, 0, stream>>>(mi, Wm1t, bm1, nh1);
    k5_mlp2<<<64, 512, 0, stream>>>(nh1, Wm2t, bm2, h);
  }
}

// Round 2
// 3366.276 us; speedup vs baseline: 2.9843x; 2.9843x over previous
//
#include <hip/hip_runtime.h>

// ---- problem dims ----
#define NB 4096    // total peds (B)
#define HD 128     // H
#define ED 64      // E
#define NF 128     // frames
#define NP 32      // peds/frame
#define TSTEPS 12

typedef __attribute__((ext_vector_type(8))) short short8;
typedef __attribute__((ext_vector_type(8))) __bf16 bf16x8;
typedef __attribute__((ext_vector_type(8))) _Float16 f16x8;
typedef __attribute__((ext_vector_type(4))) float f32x4;

#define MFMA16(a, b, c) __builtin_amdgcn_mfma_f32_16x16x32_bf16((a), (b), (c), 0, 0, 0)
#define MFMAH(a, b, c)  __builtin_amdgcn_mfma_f32_16x16x32_f16((a), (b), (c), 0, 0, 0)

__device__ __forceinline__ unsigned short f2bf(float f) {
  unsigned int x = __float_as_uint(f);
  x += 0x7fffu + ((x >> 16) & 1u);
  return (unsigned short)(x >> 16);
}

__device__ __forceinline__ float sigm(float x) { return 1.0f / (1.0f + expf(-x)); }

// ---------------- pre-pass packs ----------------

// Transpose W (K x N, fp32) -> Wt (N x K, bf16), 32x32 LDS tiles.
__global__ __launch_bounds__(256) void k_transpose_bf(const float* __restrict__ W,
                                                      unsigned short* __restrict__ Wt,
                                                      int K, int N) {
  __shared__ float t[32][33];
  int nb = blockIdx.x * 32, kb = blockIdx.y * 32;
  int tx = threadIdx.x & 31, ty = threadIdx.x >> 5;  // 8 rows of 32
  #pragma unroll
  for (int r = 0; r < 32; r += 8)
    t[ty + r][tx] = W[(size_t)(kb + ty + r) * N + nb + tx];
  __syncthreads();
  #pragma unroll
  for (int r = 0; r < 32; r += 8)
    Wt[(size_t)(nb + ty + r) * K + kb + tx] = f2bf(t[tx][ty + r]);
}

// Transpose W (K x N, fp32) -> Wt (N x K, f16)
__global__ __launch_bounds__(256) void k_transpose_f16(const float* __restrict__ W,
                                                       _Float16* __restrict__ Wt,
                                                       int K, int N) {
  __shared__ float t[32][33];
  int nb = blockIdx.x * 32, kb = blockIdx.y * 32;
  int tx = threadIdx.x & 31, ty = threadIdx.x >> 5;
  #pragma unroll
  for (int r = 0; r < 32; r += 8)
    t[ty + r][tx] = W[(size_t)(kb + ty + r) * N + nb + tx];
  __syncthreads();
  #pragma unroll
  for (int r = 0; r < 32; r += 8)
    Wt[(size_t)(nb + ty + r) * K + kb + tx] = (_Float16)t[tx][ty + r];
}

// WihT[64][512], WhhT[128][512] fp32 transposes (small, once per call)
__global__ __launch_bounds__(256) void k_pack_lstm_w(const float* __restrict__ Wih,
                                                     const float* __restrict__ Whh,
                                                     float* __restrict__ WihT,
                                                     float* __restrict__ WhhT) {
  int idx = blockIdx.x * 256 + threadIdx.x;
  if (idx < 64 * 512) { int k = idx >> 9, n = idx & 511; WihT[idx] = Wih[n * 64 + k]; }
  if (idx < 128 * 512) { int k = idx >> 9, n = idx & 511; WhhT[idx] = Whh[n * 128 + k]; }
}

// Wpp[n][2] = (W_pe @ W_p1[:64])^T ; cvec[n] = b_pe @ W_p1[:64,n] + b_p1[n]
__global__ __launch_bounds__(256) void k_pack_wpp(const float* __restrict__ Wpe,
                                                  const float* __restrict__ bpe,
                                                  const float* __restrict__ Wp1,
                                                  const float* __restrict__ bp1,
                                                  float* __restrict__ Wpp,
                                                  float* __restrict__ cvec) {
  int n = blockIdx.x * 256 + threadIdx.x;
  if (n >= 512) return;
  float s0 = 0.f, s1 = 0.f, sc = 0.f;
  for (int k = 0; k < 64; ++k) {
    float w = Wp1[k * 512 + n];
    s0 += Wpe[k] * w;
    s1 += Wpe[64 + k] * w;
    sc += bpe[k] * w;
  }
  Wpp[n * 2] = s0; Wpp[n * 2 + 1] = s1; cvec[n] = sc + bp1[n];
}

// x0 = obs_final_pos_rel @ W_emb + b_emb
__global__ __launch_bounds__(256) void k_x0(const float* __restrict__ ofr,
                                            const float* __restrict__ Wemb,
                                            const float* __restrict__ bemb,
                                            float* __restrict__ x) {
  int idx = blockIdx.x * 256 + threadIdx.x;
  if (idx >= NB * ED) return;
  int row = idx >> 6, e = idx & 63;
  x[idx] = bemb[e] + ofr[row * 2] * Wemb[e] + ofr[row * 2 + 1] * Wemb[64 + e];
}

// ---------------- per-step kernels ----------------

// K1: LSTM cell + rel/curr pos + x_new + output writes. 8 rows/block, 256 thr.
__global__ __launch_bounds__(256) void k1_lstm(
    const float* __restrict__ x, const float* __restrict__ hin, const float* __restrict__ cin,
    const float* __restrict__ WihT, const float* __restrict__ WhhT,
    const float* __restrict__ bih, const float* __restrict__ bhh,
    const float* __restrict__ Wpos, const float* __restrict__ bpos,
    const float* __restrict__ Wemb, const float* __restrict__ bemb,
    const float* __restrict__ lastpos,
    float* __restrict__ cout, float* __restrict__ hnew, unsigned short* __restrict__ mi,
    float* __restrict__ posout, float* __restrict__ xout,
    float* __restrict__ outc, float* __restrict__ outr) {
  __shared__ float xh[8][192];
  __shared__ float hnl[8][128];
  __shared__ float rp[8][2];
  int tid = threadIdx.x;
  int r0 = blockIdx.x * 8;
  for (int idx = tid; idx < 8 * 192; idx += 256) {
    int r = idx / 192, k = idx % 192;
    xh[r][k] = (k < 64) ? x[(r0 + r) * 64 + k] : hin[(r0 + r) * 128 + (k - 64)];
  }
  __syncthreads();
  int j = tid & 127, rg = tid >> 7;
  float acc0[4], acc1[4], acc2[4], acc3[4];
  {
    float b0 = bih[j] + bhh[j];
    float b1 = bih[128 + j] + bhh[128 + j];
    float b2 = bih[256 + j] + bhh[256 + j];
    float b3 = bih[384 + j] + bhh[384 + j];
    #pragma unroll
    for (int r = 0; r < 4; ++r) { acc0[r] = b0; acc1[r] = b1; acc2[r] = b2; acc3[r] = b3; }
  }
  for (int k = 0; k < 64; ++k) {
    float w0 = WihT[k * 512 + j], w1 = WihT[k * 512 + 128 + j],
          w2 = WihT[k * 512 + 256 + j], w3 = WihT[k * 512 + 384 + j];
    #pragma unroll
    for (int r = 0; r < 4; ++r) {
      float xv = xh[rg * 4 + r][k];
      acc0[r] += w0 * xv; acc1[r] += w1 * xv; acc2[r] += w2 * xv; acc3[r] += w3 * xv;
    }
  }
  for (int k = 0; k < 128; ++k) {
    float w0 = WhhT[k * 512 + j], w1 = WhhT[k * 512 + 128 + j],
          w2 = WhhT[k * 512 + 256 + j], w3 = WhhT[k * 512 + 384 + j];
    #pragma unroll
    for (int r = 0; r < 4; ++r) {
      float hv = xh[rg * 4 + r][64 + k];
      acc0[r] += w0 * hv; acc1[r] += w1 * hv; acc2[r] += w2 * hv; acc3[r] += w3 * hv;
    }
  }
  #pragma unroll
  for (int r = 0; r < 4; ++r) {
    int row = r0 + rg * 4 + r;
    float ig = sigm(acc0[r]), fg = sigm(acc1[r]), gg = tanhf(acc2[r]), og = sigm(acc3[r]);
    float cn = fg * cin[row * 128 + j] + ig * gg;
    float hv = og * tanhf(cn);
    cout[row * 128 + j] = cn;
    hnew[row * 128 + j] = hv;
    mi[(size_t)row * 1152 + j] = f2bf(hv);
    hnl[rg * 4 + r][j] = hv;
  }
  __syncthreads();
  if (tid < 16) {
    int r = tid >> 1, d = tid & 1, row = r0 + r;
    float s = bpos[d];
    for (int k = 0; k < 128; ++k) s += hnl[r][k] * Wpos[k * 2 + d];
    float cur = s + lastpos[row * 2 + d];
    rp[r][d] = s;
    posout[row * 2 + d] = cur;
    outc[row * 2 + d] = cur;
    outr[row * 2 + d] = s;
  }
  __syncthreads();
  for (int idx = tid; idx < 8 * 64; idx += 256) {
    int r = idx >> 6, e = idx & 63;
    xout[(r0 + r) * 64 + e] = bemb[e] + rp[r][0] * Wemb[e] + rp[r][1] * Wemb[64 + e];
  }
}

// K2: u[b][n] = pos_b.Wpp[:,n] + h_b.Wp1[64:,n] + cvec[n] ; v[b][n] = pos_b.Wpp[:,n]
// outputs in f16 for the k3 f16 MFMA path
__global__ __launch_bounds__(256) void k2_uv(
    const float* __restrict__ hnew, const float* __restrict__ pos,
    const float* __restrict__ Wp1, const float* __restrict__ Wpp,
    const float* __restrict__ cvec, _Float16* __restrict__ u16, _Float16* __restrict__ v16) {
  __shared__ float h8[8][128];
  __shared__ float p8[8][2];
  int tid = threadIdx.x, r0 = blockIdx.x * 8;
  for (int idx = tid; idx < 1024; idx += 256) {
    int r = idx >> 7, k = idx & 127;
    h8[r][k] = hnew[(r0 + r) * 128 + k];
  }
  if (tid < 16) p8[tid >> 1][tid & 1] = pos[r0 * 2 + tid];
  __syncthreads();
  int n = tid, n2 = tid + 256;
  float aA[8], aB[8];
  #pragma unroll
  for (int r = 0; r < 8; ++r) { aA[r] = 0.f; aB[r] = 0.f; }
  for (int k = 0; k < 128; ++k) {
    float wA = Wp1[(64 + k) * 512 + n], wB = Wp1[(64 + k) * 512 + n2];
    #pragma unroll
    for (int r = 0; r < 8; ++r) { aA[r] += wA * h8[r][k]; aB[r] += wB * h8[r][k]; }
  }
  float wp0A = Wpp[n * 2], wp1A = Wpp[n * 2 + 1], cA = cvec[n];
  float wp0B = Wpp[n2 * 2], wp1B = Wpp[n2 * 2 + 1], cB = cvec[n2];
  #pragma unroll
  for (int r = 0; r < 8; ++r) {
    int row = r0 + r;
    float t0 = p8[r][0] * wp0A + p8[r][1] * wp1A;
    v16[(size_t)row * 512 + n] = (_Float16)t0;
    u16[(size_t)row * 512 + n] = (_Float16)(t0 + aA[r] + cA);
    float t1 = p8[r][0] * wp0B + p8[r][1] * wp1B;
    v16[(size_t)row * 512 + n2] = (_Float16)t1;
    u16[(size_t)row * 512 + n2] = (_Float16)(t1 + aB[r] + cB);
  }
}

// K3 v2: pool_h[f,i,n] = relu(max_j ( relu(u_j - v_i) @ Wp2 )[n] + bp2[n])
// grid 4096 = f(128) x iblk(8) x nblk(4); 512 thr = 8 waves (4 i x 2 n-halves of 128)
// LDS: u-frame f16 (shared by all waves), v rows, double-buffered B chunk (256 x 32).
// A fragments built on the fly with packed f16 ops; f16 MFMA 16x16x32.
#define ULD 520  // u/v LDS row stride (f16 elems) -> 260 dwords, bank-balanced
#define BLD 40   // B LDS row stride  (f16 elems) -> 20 dwords,  bank-balanced
__global__ __launch_bounds__(512, 4) void k3_pool(
    const _Float16* __restrict__ u16, const _Float16* __restrict__ v16,
    const _Float16* __restrict__ Bt, const float* __restrict__ bp2,
    unsigned short* __restrict__ mi) {
  __shared__ _Float16 u_lds[32 * ULD];        // 33,280 B
  __shared__ _Float16 v_lds[4 * ULD];         //  4,160 B
  __shared__ _Float16 b_lds[2][256 * BLD];    // 40,960 B
  int bid = blockIdx.x;
  int f = bid & 127, iblk = (bid >> 7) & 7, nblk = bid >> 10;
  int tid = threadIdx.x, wid = tid >> 6, lane = tid & 63;
  int c = lane & 15, q = lane >> 4;
  int i_loc = wid >> 1;        // 0..3
  int nh = wid & 1;            // which 128-col half

  // ---- prologue staging ----
  #pragma unroll
  for (int t = 0; t < 4; ++t) {
    int unit = tid + t * 512;            // 0..2047 16B-units of the u frame
    int row = unit >> 6, colu = unit & 63;
    f16x8 val = *(const f16x8*)(u16 + (size_t)(f * 32 + row) * 512 + colu * 8);
    *(f16x8*)(u_lds + row * ULD + colu * 8) = val;
  }
  if (tid < 256) {
    int row = tid >> 6, colu = tid & 63;
    f16x8 val = *(const f16x8*)(v16 + (size_t)(f * 32 + iblk * 4 + row) * 512 + colu * 8);
    *(f16x8*)(v_lds + row * ULD + colu * 8) = val;
  }
  int br = tid >> 1, bh = tid & 1;       // B staging: row 0..255, 32B half
  const _Float16* gbase = Bt + (size_t)(nblk * 256 + br) * 512 + bh * 16;
  {
    f16x8 b0 = *(const f16x8*)(gbase);
    f16x8 b1 = *(const f16x8*)(gbase + 8);
    _Float16* d = b_lds[0] + br * BLD + bh * 16;
    *(f16x8*)(d) = b0;
    *(f16x8*)(d + 8) = b1;
  }
  __syncthreads();

  f32x4 acc[2][8];
  #pragma unroll
  for (int a = 0; a < 2; ++a)
    #pragma unroll
    for (int b = 0; b < 8; ++b) acc[a][b] = (f32x4){0.f, 0.f, 0.f, 0.f};

  const _Float16* up0 = u_lds + c * ULD;
  const _Float16* up1 = u_lds + (c + 16) * ULD;
  const _Float16* vp  = v_lds + i_loc * ULD;
  const _Float16* blb = b_lds[0] + (nh * 128 + c) * BLD + q * 8;
  int bufstride = 256 * BLD;

  #pragma unroll
  for (int ks = 0; ks < 16; ++ks) {
    f16x8 s0, s1;
    if (ks < 15) {                       // prefetch next B chunk (T14: issue early)
      const _Float16* gb = gbase + (ks + 1) * 32;
      s0 = *(const f16x8*)(gb);
      s1 = *(const f16x8*)(gb + 8);
    }
    int k0 = ks * 32 + q * 8;
    f16x8 uv0 = *(const f16x8*)(up0 + k0);
    f16x8 uv1 = *(const f16x8*)(up1 + k0);
    f16x8 vv  = *(const f16x8*)(vp + k0);
    f16x8 a0 = uv0 - vv;
    f16x8 a1 = uv1 - vv;
    a0 = __builtin_elementwise_max(a0, (f16x8)(_Float16)0);
    a1 = __builtin_elementwise_max(a1, (f16x8)(_Float16)0);
    const _Float16* bl = blb + (ks & 1) * bufstride;
    #pragma unroll
    for (int nt = 0; nt < 8; ++nt) {
      f16x8 bf = *(const f16x8*)(bl + nt * 16 * BLD);
      acc[0][nt] = MFMAH(a0, bf, acc[0][nt]);
      acc[1][nt] = MFMAH(a1, bf, acc[1][nt]);
    }
    __syncthreads();                     // all waves done reading buf (ks-1)&1
    if (ks < 15) {
      _Float16* d = b_lds[(ks + 1) & 1] + br * BLD + bh * 16;
      *(f16x8*)(d) = s0;
      *(f16x8*)(d + 8) = s1;
    }
    __syncthreads();                     // next buffer ready
  }

  int i = iblk * 4 + i_loc;
  #pragma unroll
  for (int nt = 0; nt < 8; ++nt) {
    float m = acc[0][nt][0];
    #pragma unroll
    for (int r = 0; r < 4; ++r) { m = fmaxf(m, acc[0][nt][r]); m = fmaxf(m, acc[1][nt][r]); }
    m = fmaxf(m, __shfl_xor(m, 16));
    m = fmaxf(m, __shfl_xor(m, 32));
    int n = nblk * 256 + nh * 128 + nt * 16 + c;
    m = fmaxf(m + bp2[n], 0.0f);
    if (q == 0) mi[(size_t)(f * 32 + i) * 1152 + 128 + n] = f2bf(m);
  }
}

// K4: nh1 = relu(mi @ W_m1 + b_m1), M=4096 K=1152 N=1024 (bf16 MFMA)
__global__ __launch_bounds__(512) void k4_mlp1(
    const unsigned short* __restrict__ mi, const unsigned short* __restrict__ Wt,
    const float* __restrict__ bm1, unsigned short* __restrict__ nh1) {
  int bid = blockIdx.x;
  int mb = bid & 63, nb = bid >> 6;
  int tid = threadIdx.x, wid = tid >> 6, lane = tid & 63;
  int row0 = mb * 64 + (wid >> 2) * 32;
  int nc0 = nb * 256 + (wid & 3) * 64;
  int c = lane & 15, q = lane >> 4;
  const unsigned short* a0p = mi + (size_t)(row0 + c) * 1152;
  const unsigned short* a1p = a0p + 16 * 1152;
  const unsigned short* bb = Wt + (size_t)(nc0 + c) * 1152;
  f32x4 acc[2][4];
  #pragma unroll
  for (int a = 0; a < 2; ++a)
    #pragma unroll
    for (int b = 0; b < 4; ++b) acc[a][b] = (f32x4){0.f, 0.f, 0.f, 0.f};
  for (int ks = 0; ks < 36; ++ks) {
    int k0 = ks * 32 + q * 8;
    bf16x8 a0 = *(const bf16x8*)(a0p + k0);
    bf16x8 a1 = *(const bf16x8*)(a1p + k0);
    #pragma unroll
    for (int nt = 0; nt < 4; ++nt) {
      bf16x8 bf = *(const bf16x8*)(bb + (size_t)nt * 16 * 1152 + k0);
      acc[0][nt] = MFMA16(a0, bf, acc[0][nt]);
      acc[1][nt] = MFMA16(a1, bf, acc[1][nt]);
    }
  }
  #pragma unroll
  for (int mt = 0; mt < 2; ++mt)
    #pragma unroll
    for (int nt = 0; nt < 4; ++nt)
      #pragma unroll
      for (int r = 0; r < 4; ++r) {
        int row = row0 + mt * 16 + q * 4 + r;
        int col = nc0 + nt * 16 + c;
        float val = fmaxf(acc[mt][nt][r] + bm1[col], 0.f);
        nh1[(size_t)row * 1024 + col] = f2bf(val);
      }
}

// K5: h = relu(nh1 @ W_m2 + b_m2), M=4096 K=1024 N=128
__global__ __launch_bounds__(512) void k5_mlp2(
    const unsigned short* __restrict__ nh1, const unsigned short* __restrict__ Wt,
    const float* __restrict__ bm2, float* __restrict__ hout) {
  int bid = blockIdx.x;
  int tid = threadIdx.x, wid = tid >> 6, lane = tid & 63;
  int row0 = bid * 64 + (wid >> 1) * 16;
  int nc0 = (wid & 1) * 64;
  int c = lane & 15, q = lane >> 4;
  const unsigned short* ap = nh1 + (size_t)(row0 + c) * 1024;
  const unsigned short* bb = Wt + (size_t)(nc0 + c) * 1024;
  f32x4 acc[4];
  #pragma unroll
  for (int b = 0; b < 4; ++b) acc[b] = (f32x4){0.f, 0.f, 0.f, 0.f};
  for (int ks = 0; ks < 32; ++ks) {
    int k0 = ks * 32 + q * 8;
    bf16x8 a = *(const bf16x8*)(ap + k0);
    #pragma unroll
    for (int nt = 0; nt < 4; ++nt) {
      bf16x8 bf = *(const bf16x8*)(bb + (size_t)nt * 16 * 1024 + k0);
      acc[nt] = MFMA16(a, bf, acc[nt]);
    }
  }
  #pragma unroll
  for (int nt = 0; nt < 4; ++nt)
    #pragma unroll
    for (int r = 0; r < 4; ++r) {
      int row = row0 + q * 4 + r;
      int col = nc0 + nt * 16 + c;
      hout[(size_t)row * 128 + col] = fmaxf(acc[nt][r] + bm2[col], 0.f);
    }
}

// ---------------- host ----------------

extern "C" void kernel_launch(void* const* d_in, const int* in_sizes, int n_in,
                              void* d_out, int out_size, void* d_ws, size_t ws_size,
                              hipStream_t stream) {
  const float* h0   = (const float*)d_in[0];
  const float* c0   = (const float*)d_in[1];
  const float* ofp  = (const float*)d_in[2];
  const float* ofr  = (const float*)d_in[3];
  const float* Wemb = (const float*)d_in[4];
  const float* bemb = (const float*)d_in[5];
  const float* Wih  = (const float*)d_in[6];
  const float* Whh  = (const float*)d_in[7];
  const float* bih  = (const float*)d_in[8];
  const float* bhh  = (const float*)d_in[9];
  const float* Wpos = (const float*)d_in[10];
  const float* bpos = (const float*)d_in[11];
  const float* Wpe  = (const float*)d_in[12];
  const float* bpe  = (const float*)d_in[13];
  const float* Wp1  = (const float*)d_in[14];
  const float* bp1  = (const float*)d_in[15];
  const float* Wp2  = (const float*)d_in[16];
  const float* bp2  = (const float*)d_in[17];
  const float* Wm1  = (const float*)d_in[18];
  const float* bm1  = (const float*)d_in[19];
  const float* Wm2  = (const float*)d_in[20];
  const float* bm2  = (const float*)d_in[21];

  char* ws = (char*)d_ws;
  size_t off = 0;
  auto alloc = [&](size_t bytes) {
    char* p = ws + off;
    off += (bytes + 255) & ~(size_t)255;
    return p;
  };
  float* h    = (float*)alloc((size_t)NB * HD * 4);
  float* cst  = (float*)alloc((size_t)NB * HD * 4);
  float* hnew = (float*)alloc((size_t)NB * HD * 4);
  float* xbuf = (float*)alloc((size_t)NB * ED * 4);
  float* pos  = (float*)alloc((size_t)NB * 2 * 4);
  _Float16* u16 = (_Float16*)alloc((size_t)NB * 512 * 2);
  _Float16* v16 = (_Float16*)alloc((size_t)NB * 512 * 2);
  unsigned short* mi   = (unsigned short*)alloc((size_t)NB * 1152 * 2);
  unsigned short* nh1  = (unsigned short*)alloc((size_t)NB * 1024 * 2);
  float* WihT = (float*)alloc(64 * 512 * 4);
  float* WhhT = (float*)alloc(128 * 512 * 4);
  float* Wpp  = (float*)alloc(512 * 2 * 4);
  float* cvec = (float*)alloc(512 * 4);
  _Float16* Bt2 = (_Float16*)alloc((size_t)1024 * 512 * 2);
  unsigned short* Wm1t = (unsigned short*)alloc((size_t)1024 * 1152 * 2);
  unsigned short* Wm2t = (unsigned short*)alloc((size_t)128 * 1024 * 2);

  float* outc = (float*)d_out;
  float* outr = outc + (size_t)TSTEPS * NB * 2;

  k_pack_lstm_w<<<256, 256, 0, stream>>>(Wih, Whh, WihT, WhhT);
  k_pack_wpp<<<2, 256, 0, stream>>>(Wpe, bpe, Wp1, bp1, Wpp, cvec);
  k_transpose_f16<<<dim3(1024 / 32, 512 / 32), 256, 0, stream>>>(Wp2, Bt2, 512, 1024);
  k_transpose_bf<<<dim3(1024 / 32, 1152 / 32), 256, 0, stream>>>(Wm1, Wm1t, 1152, 1024);
  k_transpose_bf<<<dim3(128 / 32, 1024 / 32), 256, 0, stream>>>(Wm2, Wm2t, 1024, 128);
  k_x0<<<NB * ED / 256, 256, 0, stream>>>(ofr, Wemb, bemb, xbuf);

  for (int t = 0; t < TSTEPS; ++t) {
    const float* hin = (t == 0) ? h0 : h;
    const float* cin = (t == 0) ? c0 : cst;
    const float* lp  = (t == 0) ? ofp : pos;
    k1_lstm<<<NB / 8, 256, 0, stream>>>(xbuf, hin, cin, WihT, WhhT, bih, bhh, Wpos, bpos,
                                        Wemb, bemb, lp, cst, hnew, mi, pos, xbuf,
                                        outc + (size_t)t * NB * 2, outr + (size_t)t * NB * 2);
    k2_uv<<<NB / 8, 256, 0, stream>>>(hnew, pos, Wp1, Wpp, cvec, u16, v16);
    k3_pool<<<4096, 512, 0, stream>>>(u16, v16, Bt2, bp2, mi);
    k4_mlp1<<<256, 512, 0, stream>>>(mi, Wm1t, bm1, nh1);
    k5_mlp2<<<64, 512, 0, stream>>>(nh1, Wm2t, bm2, h);
  }
}